// Round 1
// baseline (235.138 us; speedup 1.0000x reference)
//
#include <hip/hip_runtime.h>

typedef unsigned short u16;
typedef unsigned int   u32;
typedef unsigned long long u64;
typedef long long i64;

typedef __attribute__((ext_vector_type(8))) short short8;
typedef __attribute__((ext_vector_type(4))) float f32x4;

#define DEV static __device__ __forceinline__

// ---------------- constants ----------------
// POW10F[p][k] = 10^k mod p  (primes 7,11,13,17,19,23,29,31,37), matches reference f32 table
__constant__ float POW10F[9][10] = {
  {1,3,2,6,4,5,1,3,2,6},
  {1,10,1,10,1,10,1,10,1,10},
  {1,10,9,12,3,4,1,10,9,12},
  {1,10,15,14,4,6,9,5,16,7},
  {1,10,5,12,6,3,11,15,17,18},
  {1,10,8,11,18,19,6,14,2,20},
  {1,10,13,14,24,8,22,17,25,18},
  {1,10,7,8,18,25,2,20,14,16},
  {1,10,26,1,10,26,1,10,26,1},
};

#define M_TOTAL  247357937827ull
#define M_HALF   123678968913ull

// ---------------- helpers ----------------
DEV u16 f2bf_rne(float f){
  u32 u = __float_as_uint(f);
  return (u16)((u + 0x7FFFu + ((u >> 16) & 1u)) >> 16);
}
DEV float bf2f(u16 v){ return __uint_as_float(((u32)v) << 16); }

DEV short8 pack_bf16(float4 a, float4 b){
  union { short8 s; u32 u[4]; } r;
  r.u[0] = (__float_as_uint(a.x) >> 16) | (__float_as_uint(a.y) & 0xFFFF0000u);
  r.u[1] = (__float_as_uint(a.z) >> 16) | (__float_as_uint(a.w) & 0xFFFF0000u);
  r.u[2] = (__float_as_uint(b.x) >> 16) | (__float_as_uint(b.y) & 0xFFFF0000u);
  r.u[3] = (__float_as_uint(b.z) >> 16) | (__float_as_uint(b.w) & 0xFFFF0000u);
  return r.s;
}

DEV void load_lds16(const void* g, void* l){
  // async global->LDS, 16B/lane; LDS dest is wave-uniform base + lane*16
  __builtin_amdgcn_global_load_lds((const __attribute__((address_space(1))) void*)g,
                                   (__attribute__((address_space(3))) void*)l, 16, 0, 0);
}

DEV int modpow6(int b, int e, int p){
  int res = 1; b %= p;
  #pragma unroll
  for (int i = 0; i < 6; ++i){
    if (e & 1) res = (res * b) % p;
    b = (b * b) % p;
    e >>= 1;
  }
  return res;
}

// ---------------- kernel 0: per-batch scan ----------------
__global__ void scan_kernel(const int* __restrict__ ids, int* __restrict__ op_idx,
                            float* __restrict__ has_eq){
  __shared__ int smin[256];
  __shared__ int seq[256];
  int b = blockIdx.x, tid = threadIdx.x;
  int best = 2048, eq = 0;
  for (int i = tid; i < 2048; i += 256){
    int t = ids[b * 2048 + i];
    if (t >= 20 && t < 25) best = min(best, i);
    eq |= (t == 28) ? 1 : 0;
  }
  smin[tid] = best; seq[tid] = eq;
  __syncthreads();
  for (int s = 128; s > 0; s >>= 1){
    if (tid < s){ smin[tid] = min(smin[tid], smin[tid + s]); seq[tid] |= seq[tid + s]; }
    __syncthreads();
  }
  if (tid == 0){
    int op = -1;
    if (smin[0] < 2048) op = ids[b * 2048 + smin[0]] - 20;
    op_idx[b] = op;
    has_eq[b] = seq[0] ? 1.0f : 0.0f;
  }
}

// ---------------- kernel 1: weight repack (MFMA fragment-block layout) ----------------
// w1f: 24 k-steps x 8 n-blocks, each block = 64 lanes x 8 bf16 (B-frag of 16x16x32)
// w2f: 4 k-steps x 13 n-blocks (N padded 200->208)
__global__ void prep_kernel(const float* __restrict__ W1, const float* __restrict__ W2,
                            u16* __restrict__ w1f, u16* __restrict__ w2f){
  int tid = blockIdx.x * 256 + threadIdx.x;
  if (tid < 12288){
    int blk = tid >> 6, L = tid & 63;
    int T = blk >> 3, b = blk & 7;
    int q = L >> 4, ln = L & 15;
    #pragma unroll
    for (int j = 0; j < 8; ++j){
      int k = 32 * T + 8 * q + j;
      int n = 16 * b + ln;
      w1f[(size_t)blk * 512 + L * 8 + j] = f2bf_rne(W1[k * 128 + n]);
    }
  } else if (tid < 12288 + 3328){
    int t2 = tid - 12288;
    int blk = t2 >> 6, L = t2 & 63;
    int t = blk / 13, b2 = blk % 13;
    int q = L >> 4, ln = L & 15;
    #pragma unroll
    for (int j = 0; j < 8; ++j){
      int k = 32 * t + 8 * q + j;
      int n = 16 * b2 + ln;
      w2f[(size_t)blk * 512 + L * 8 + j] = (n < 200) ? f2bf_rne(W2[k * 200 + n]) : (u16)0;
    }
  }
}

// ---------------- kernel 2: fused GEMM1 + GEMM2 + softmax + residue arithmetic ----------------
__launch_bounds__(256, 2)
__global__ void pass1_kernel(const float* __restrict__ h, const u16* __restrict__ w1f,
                             const u16* __restrict__ w2f, const float* __restrict__ b1,
                             const float* __restrict__ b2, const int* __restrict__ op_idx_ws,
                             float* __restrict__ dout, u64* __restrict__ msbp){
  __shared__ u16 w1buf[16384];        // 32KB: 32 frag-blocks of 1KB; reused for logits after GEMM1
  __shared__ u16 hidf[4][2048];       // per-wave hid A-frag blocks (4 k-steps x 1KB)
  __shared__ float digits_s[64][20];
  __shared__ float tab_s[64][18];
  __shared__ u64 ops_s[64][5];

  const int tid = threadIdx.x;
  const int w = tid >> 6;
  const int lane = tid & 63;
  const int ln = lane & 15, q = lane >> 4;
  const int wg = blockIdx.x;
  const int tok0 = wg * 64;
  const int gtok = tok0 + w * 16 + ln;   // A-row token for GEMM1 (m = ln)

  // bias preload (per-lane)
  float b1v[8];
  #pragma unroll
  for (int b = 0; b < 8; ++b) b1v[b] = b1[ln + 16 * b];
  float b2v[13];
  #pragma unroll
  for (int b = 0; b < 13; ++b){ int n = ln + 16 * b; b2v[b] = (n < 200) ? b2[n] : 0.0f; }

  // ---- GEMM1: hid = relu(h @ W1 + b1), bf16 MFMA 16x16x32, 6 K-chunks of 128 ----
  f32x4 acc[8];
  #pragma unroll
  for (int b = 0; b < 8; ++b) acc[b] = (f32x4)0.0f;

  const float* hrow = h + (size_t)gtok * 768;
  for (int c = 0; c < 6; ++c){
    float4 xa[4], xb[4];
    const float4* ap = (const float4*)(hrow + c * 128);
    #pragma unroll
    for (int t = 0; t < 4; ++t){
      xa[t] = ap[t * 8 + q * 2];
      xb[t] = ap[t * 8 + q * 2 + 1];
    }
    __syncthreads();   // previous chunk fully consumed
    #pragma unroll
    for (int i = 0; i < 8; ++i){
      int blk = w * 8 + i;
      load_lds16(w1f + (size_t)(c * 32 + blk) * 512 + lane * 8, &w1buf[blk * 512]);
    }
    __syncthreads();   // staging complete (barrier drains vmcnt)
    short8 af[4];
    #pragma unroll
    for (int t = 0; t < 4; ++t) af[t] = pack_bf16(xa[t], xb[t]);
    #pragma unroll
    for (int t = 0; t < 4; ++t){
      #pragma unroll
      for (int b = 0; b < 8; ++b){
        short8 bf = *(const short8*)&w1buf[(t * 8 + b) * 512 + lane * 8];
        acc[b] = __builtin_amdgcn_mfma_f32_16x16x32_bf16(af[t], bf, acc[b], 0, 0, 0);
      }
    }
  }

  // ---- relu+bias, dump hid into this wave's A-frag layout (wave-private LDS) ----
  // D layout: value at (m = q*4+r, k2 = 16b+ln); consumer frag addr: t2=k2>>5, L2=16*((k2>>3)&3)+m, j=k2&7
  #pragma unroll
  for (int b = 0; b < 8; ++b){
    int t2 = b >> 1;
    int q2 = ((b & 1) << 1) | (ln >> 3);
    int j = ln & 7;
    #pragma unroll
    for (int r = 0; r < 4; ++r){
      float v = acc[b][r] + b1v[b];
      v = fmaxf(v, 0.0f);
      int L2 = (q2 << 4) | (q * 4 + r);
      hidf[w][t2 * 512 + L2 * 8 + j] = (u16)(__float_as_uint(v) >> 16);
    }
  }
  __syncthreads();

  // ---- GEMM2: logits = hid @ W2 + b2 (N padded to 208), B-frags from global w2f (L2-hot) ----
  short8 a2[4];
  #pragma unroll
  for (int t = 0; t < 4; ++t) a2[t] = *(const short8*)&hidf[w][t * 512 + lane * 8];
  f32x4 acc2[13];
  #pragma unroll
  for (int b = 0; b < 13; ++b) acc2[b] = (f32x4)0.0f;
  #pragma unroll
  for (int b = 0; b < 13; ++b){
    #pragma unroll
    for (int t = 0; t < 4; ++t){
      short8 bf = *(const short8*)(w2f + (size_t)(t * 13 + b) * 512 + lane * 8);
      acc2[b] = __builtin_amdgcn_mfma_f32_16x16x32_bf16(a2[t], bf, acc2[b], 0, 0, 0);
    }
  }

  __syncthreads();   // all waves done reading w1buf (GEMM1) -> safe to reuse for logits

  // dump logits (bf16) into w1buf: per-wave region 4096 u16, row stride 212
  #pragma unroll
  for (int b = 0; b < 13; ++b){
    #pragma unroll
    for (int r = 0; r < 4; ++r){
      float v = acc2[b][r] + b2v[b];
      w1buf[w * 4096 + (q * 4 + r) * 212 + ln + 16 * b] = (u16)(__float_as_uint(v) >> 16);
    }
  }
  __syncthreads();

  // ---- softmax + expected digit, per (token, slot) : 64*20 = 1280 tasks ----
  #pragma unroll
  for (int i = 0; i < 5; ++i){
    int task = tid + i * 256;
    int tok = task / 20, slot = task % 20;
    const u16* lp = &w1buf[(tok >> 4) * 4096 + (tok & 15) * 212 + slot * 10];
    float v[10];
    #pragma unroll
    for (int k = 0; k < 10; ++k) v[k] = bf2f(lp[k]);
    float mx = v[0];
    #pragma unroll
    for (int k = 1; k < 10; ++k) mx = fmaxf(mx, v[k]);
    float s = 0.0f, sd = 0.0f;
    #pragma unroll
    for (int k = 0; k < 10; ++k){
      float e = __expf(v[k] - mx);
      s += e; sd += e * (float)k;
    }
    float dig = sd / s;
    digits_s[tok][slot] = dig;
    int gt = tok0 + tok;
    int o = slot / 10, k10 = slot % 10;
    dout[(size_t)25165824 + (size_t)o * 327680 + (size_t)gt * 10 + k10] = dig;
  }
  __syncthreads();

  // ---- t_p = sum_k d_k * (10^k mod p) per (token, a/b, prime): 1152 tasks ----
  #pragma unroll
  for (int i = 0; i < 5; ++i){
    int task = tid + i * 256;
    if (task < 1152){
      int tok = task / 18, rm = task % 18;
      int ab = rm / 9, pi = rm % 9;
      float t = 0.0f;
      #pragma unroll
      for (int k = 0; k < 10; ++k) t += digits_s[tok][ab * 10 + k] * POW10F[pi][k];
      tab_s[tok][ab * 9 + pi] = t;
    }
  }
  __syncthreads();

  // ---- residue arithmetic, all 5 ops per token: 320 tasks (wave-uniform op) ----
  {
    constexpr int PR[9] = {7, 11, 13, 17, 19, 23, 29, 31, 37};
    constexpr u64 CRTC[9] = {
      35336848261ull, 224870852570ull, 114165202074ull, 218257003965ull,
      78113032998ull, 53773464745ull, 68236672504ull, 223420072876ull, 220616539143ull
    };
    #pragma unroll
    for (int rep = 0; rep < 2; ++rep){
      int task = tid + rep * 256;
      if (task < 320){
        int op = task >> 6, tok = task & 63;
        u64 acc64 = 0;
        #pragma unroll
        for (int pi = 0; pi < 9; ++pi){
          const int p = PR[pi];
          float ta = tab_s[tok][pi], tb = tab_s[tok][9 + pi];
          int r;
          if (op == 0){
            r = __float2int_rn(ta + tb) % p;
          } else if (op == 1){
            int s = __float2int_rn(ta - tb) % p;
            r = (s < 0) ? s + p : s;
          } else {
            int ra = __float2int_rn(ta) % p;
            int rb = __float2int_rn(tb) % p;
            if (op == 2) r = (ra * rb) % p;
            else if (op == 3) r = modpow6(ra, rb, p);
            else r = (rb == 0) ? 0 : (ra * modpow6(rb, p - 2, p)) % p;
          }
          acc64 += (u64)r * CRTC[pi];
        }
        u64 n = acc64 % M_TOTAL;
        int sign = 0;
        u64 un = n;
        if (op == 1 && n > M_HALF){ sign = 1; un = M_TOTAL - n; }
        u64 pk = 0;
        #pragma unroll
        for (int k = 0; k < 10; ++k){ pk |= (un % 10ull) << (4 * k); un /= 10ull; }
        pk |= ((u64)sign) << 40;
        ops_s[tok][op] = pk;
      }
    }
  }
  __syncthreads();

  // ---- select op (uniform per WG: 64 tokens never cross batch), reorder MSB-first, pack ----
  if (tid < 64){
    int tok = tid;
    int op = op_idx_ws[wg >> 5];
    u64 pk = (op >= 0) ? ops_s[tok][op] : 0ull;
    int g[10]; int hi = -1;
    #pragma unroll
    for (int k = 0; k < 10; ++k){
      g[k] = (int)((pk >> (4 * k)) & 15ull);
      if (g[k] != 0) hi = k;
    }
    int ns = (hi >= 0) ? hi + 1 : 1;
    u64 mp = 0;
    #pragma unroll
    for (int i = 0; i < 10; ++i){
      int v = (i < ns) ? g[ns - 1 - i] : 15;   // 0xF encodes -1
      mp |= ((u64)v) << (4 * i);
    }
    mp |= ((pk >> 40) & 1ull) << 40;           // sign nibble
    msbp[tok0 + tok] = mp;
  }
}

// ---------------- kernel 3: inj = msb @ Winj + binj ; h_prime = h + g*has_eq*inj ----------------
__launch_bounds__(192)
__global__ void pass2_kernel(const float* __restrict__ h, const float* __restrict__ Winj,
                             const float* __restrict__ binj, const float* __restrict__ gate,
                             const float* __restrict__ has_eq_ws,
                             const u64* __restrict__ msbp, float* __restrict__ dout){
  __shared__ u64 smp[16];
  const int tid = threadIdx.x;
  const int tok0 = blockIdx.x * 16;
  if (tid < 16) smp[tid] = msbp[tok0 + tid];

  float4 wv[11];
  #pragma unroll
  for (int j = 0; j < 11; ++j) wv[j] = *(const float4*)(Winj + (size_t)j * 768 + tid * 4);
  float4 bj = *(const float4*)(binj + tid * 4);
  float G = has_eq_ws[tok0 >> 11] * (1.0f / (1.0f + __expf(-gate[0])));
  __syncthreads();

  #pragma unroll 4
  for (int tt = 0; tt < 16; ++tt){
    u64 mp = smp[tt];
    float v[11];
    #pragma unroll
    for (int k = 0; k < 10; ++k){
      int nib = (int)((mp >> (4 * k)) & 15ull);
      v[k] = (nib == 15) ? -1.0f : (float)nib;
    }
    v[10] = (float)((mp >> 40) & 15ull);
    float ix = bj.x, iy = bj.y, iz = bj.z, iw = bj.w;
    #pragma unroll
    for (int j = 0; j < 11; ++j){
      ix += v[j] * wv[j].x; iy += v[j] * wv[j].y;
      iz += v[j] * wv[j].z; iw += v[j] * wv[j].w;
    }
    size_t off = (size_t)(tok0 + tt) * 768 + tid * 4;
    float4 hv = *(const float4*)(h + off);
    float4 o;
    o.x = hv.x + G * ix; o.y = hv.y + G * iy;
    o.z = hv.z + G * iz; o.w = hv.w + G * iw;
    *(float4*)(dout + off) = o;
  }
}

// ---------------- launch ----------------
extern "C" void kernel_launch(void* const* d_in, const int* in_sizes, int n_in,
                              void* d_out, int out_size, void* d_ws, size_t ws_size,
                              hipStream_t stream){
  const float* h    = (const float*)d_in[0];
  const float* W1   = (const float*)d_in[1];
  const float* b1   = (const float*)d_in[2];
  const float* W2   = (const float*)d_in[3];
  const float* b2   = (const float*)d_in[4];
  const float* Winj = (const float*)d_in[5];
  const float* binj = (const float*)d_in[6];
  const float* gate = (const float*)d_in[7];
  const int*   ids  = (const int*)d_in[8];
  float* dout = (float*)d_out;

  // workspace layout (needs ~513 KB)
  char* ws = (char*)d_ws;
  int*   op_idx = (int*)(ws + 0);                 // 16 ints
  float* has_eq = (float*)(ws + 64);              // 16 floats
  u16*   w1f    = (u16*)(ws + 256);               // 196608 B
  u16*   w2f    = (u16*)(ws + 256 + 196608);      // 53248 B
  u64*   msbp   = (u64*)(ws + 250112);            // 262144 B

  scan_kernel<<<16, 256, 0, stream>>>(ids, op_idx, has_eq);
  prep_kernel<<<61, 256, 0, stream>>>(W1, W2, w1f, w2f);
  pass1_kernel<<<512, 256, 0, stream>>>(h, w1f, w2f, b1, b2, op_idx, dout, msbp);
  pass2_kernel<<<2048, 192, 0, stream>>>(h, Winj, binj, gate, has_eq, msbp, dout);
}

// Round 2
// 234.226 us; speedup vs baseline: 1.0039x; 1.0039x over previous
//
#include <hip/hip_runtime.h>

typedef unsigned short u16;
typedef unsigned int   u32;
typedef unsigned long long u64;

typedef __attribute__((ext_vector_type(8))) short short8;
typedef __attribute__((ext_vector_type(4))) float f32x4;

#define DEV static __device__ __forceinline__

// POW10F[p][k] = 10^k mod p  (primes 7,11,13,17,19,23,29,31,37)
__constant__ float POW10F[9][10] = {
  {1,3,2,6,4,5,1,3,2,6},
  {1,10,1,10,1,10,1,10,1,10},
  {1,10,9,12,3,4,1,10,9,12},
  {1,10,15,14,4,6,9,5,16,7},
  {1,10,5,12,6,3,11,15,17,18},
  {1,10,8,11,18,19,6,14,2,20},
  {1,10,13,14,24,8,22,17,25,18},
  {1,10,7,8,18,25,2,20,14,16},
  {1,10,26,1,10,26,1,10,26,1},
};

#define M_TOTAL  247357937827ull
#define M_HALF   123678968913ull

DEV u16 f2bf_rne(float f){
  u32 u = __float_as_uint(f);
  return (u16)((u + 0x7FFFu + ((u >> 16) & 1u)) >> 16);
}
DEV float bf2f(u16 v){ return __uint_as_float(((u32)v) << 16); }

DEV short8 pack_bf16(float4 a, float4 b){
  union { short8 s; u32 u[4]; } r;
  r.u[0] = (__float_as_uint(a.x) >> 16) | (__float_as_uint(a.y) & 0xFFFF0000u);
  r.u[1] = (__float_as_uint(a.z) >> 16) | (__float_as_uint(a.w) & 0xFFFF0000u);
  r.u[2] = (__float_as_uint(b.x) >> 16) | (__float_as_uint(b.y) & 0xFFFF0000u);
  r.u[3] = (__float_as_uint(b.z) >> 16) | (__float_as_uint(b.w) & 0xFFFF0000u);
  return r.s;
}

DEV void load_lds16(const void* g, void* l){
  __builtin_amdgcn_global_load_lds((const __attribute__((address_space(1))) void*)g,
                                   (__attribute__((address_space(3))) void*)l, 16, 0, 0);
}

DEV int modpow6(int b, int e, int p){
  int res = 1; b %= p;
  #pragma unroll
  for (int i = 0; i < 6; ++i){
    if (e & 1) res = (res * b) % p;
    b = (b * b) % p;
    e >>= 1;
  }
  return res;
}

// ---------------- prelude: per-batch scan (blocks 0..15) + weight repack (16..76) ----------------
__global__ void prelude_kernel(const int* __restrict__ ids, const float* __restrict__ W1,
                               const float* __restrict__ W2, int* __restrict__ op_idx,
                               float* __restrict__ has_eq, u16* __restrict__ w1f,
                               u16* __restrict__ w2f){
  __shared__ int smin[256];
  __shared__ int seq[256];
  int bid = blockIdx.x, tid = threadIdx.x;
  if (bid < 16){
    int b = bid;
    int best = 2048, eq = 0;
    for (int i = tid; i < 2048; i += 256){
      int t = ids[b * 2048 + i];
      if (t >= 20 && t < 25) best = min(best, i);
      eq |= (t == 28) ? 1 : 0;
    }
    smin[tid] = best; seq[tid] = eq;
    __syncthreads();
    for (int s = 128; s > 0; s >>= 1){
      if (tid < s){ smin[tid] = min(smin[tid], smin[tid + s]); seq[tid] |= seq[tid + s]; }
      __syncthreads();
    }
    if (tid == 0){
      int op = -1;
      if (smin[0] < 2048) op = ids[b * 2048 + smin[0]] - 20;
      op_idx[b] = op;
      has_eq[b] = seq[0] ? 1.0f : 0.0f;
    }
  } else {
    int t = (bid - 16) * 256 + tid;   // 0..15615
    if (t < 12288){
      int blk = t >> 6, L = t & 63;
      int T = blk >> 3, b = blk & 7;
      int q = L >> 4, ln = L & 15;
      #pragma unroll
      for (int j = 0; j < 8; ++j){
        int k = 32 * T + 8 * q + j;
        int n = 16 * b + ln;
        w1f[(size_t)blk * 512 + L * 8 + j] = f2bf_rne(W1[k * 128 + n]);
      }
    } else {
      int t2 = t - 12288;             // 0..3327
      int blk = t2 >> 6, L = t2 & 63;
      int ts = blk / 13, b2 = blk % 13;
      int q = L >> 4, ln = L & 15;
      #pragma unroll
      for (int j = 0; j < 8; ++j){
        int k = 32 * ts + 8 * q + j;
        int n = 16 * b2 + ln;
        w2f[(size_t)blk * 512 + L * 8 + j] = (n < 200) ? f2bf_rne(W2[k * 200 + n]) : (u16)0;
      }
    }
  }
}

// ---------------- mega: GEMM1+GEMM2+softmax+residues+select+inj+residual, one pass ----------------
__launch_bounds__(256, 2)
__global__ void mega_kernel(const float* __restrict__ h, const u16* __restrict__ w1f,
                            const u16* __restrict__ w2f, const float* __restrict__ b1,
                            const float* __restrict__ b2, const float* __restrict__ Winj,
                            const float* __restrict__ binj, const float* __restrict__ gate,
                            const int* __restrict__ op_idx_ws, const float* __restrict__ has_eq_ws,
                            float* __restrict__ dout){
  // LDS 48KB: wbuf = 2x16KB K-chunk dbuf (later: logits 32KB, later: Winj/binj overlay)
  //           tail = 16KB: hidf (GEMM2 A-frags) -> digits/tab/ops/msbv
  __shared__ __align__(16) char lds[49152];
  u16*   wbuf     = (u16*)lds;                 // 16384 u16
  char*  tail     = lds + 32768;
  float* digits_s = (float*)tail;              // [64][20] 5120B
  float* tab_s    = (float*)(tail + 5120);     // [64][18] 4608B
  u64*   ops_s    = (u64*)(tail + 9728);       // [64][5]  2560B
  float* msbv     = (float*)(tail + 12288);    // [64][12] 3072B
  u16*   hidf     = (u16*)tail;                // [4][2048] 16KB (dead before digits written)
  float* winj_s   = (float*)lds;               // 8448 floats (33792B, overlays wbuf + 1KB of tail)
  float* binj_s   = (float*)(lds + 33792);     // 768 floats

  const int tid  = threadIdx.x;
  const int w    = tid >> 6;
  const int lane = tid & 63;
  const int ln   = lane & 15, q = lane >> 4;
  const int wg   = blockIdx.x;
  const int tok0 = wg * 64;
  const int gtok = tok0 + w * 16 + ln;
  const int batch = wg >> 5;

  const int   op = op_idx_ws[batch];
  const float G  = has_eq_ws[batch] * (1.0f / (1.0f + __expf(-gate[0])));

  float b1v[8];
  #pragma unroll
  for (int b = 0; b < 8; ++b) b1v[b] = b1[ln + 16 * b];
  float b2v[13];
  #pragma unroll
  for (int b = 0; b < 13; ++b){ int n = ln + 16 * b; b2v[b] = (n < 200) ? b2[n] : 0.0f; }

  // ---- GEMM1: hid = relu(h @ W1 + b1); 12 K-chunks of 64, dbuf, ONE barrier per chunk ----
  f32x4 acc[8];
  #pragma unroll
  for (int b = 0; b < 8; ++b) acc[b] = (f32x4)0.0f;

  const float4* ap = (const float4*)(h + (size_t)gtok * 768);
  float4 xa[2], xb[2];
  // prologue: stage chunk 0 into buf0, load h chunk 0
  #pragma unroll
  for (int i = 0; i < 4; ++i){
    int bl = w * 4 + i;                 // t = bl>>3, b = bl&7, T = 0*2 + t
    load_lds16(w1f + (size_t)(((bl >> 3)) * 8 + (bl & 7)) * 512 + lane * 8,
               wbuf + bl * 512);
  }
  #pragma unroll
  for (int t = 0; t < 2; ++t){ xa[t] = ap[t * 8 + q * 2]; xb[t] = ap[t * 8 + q * 2 + 1]; }

  #pragma unroll
  for (int c = 0; c < 12; ++c){
    __syncthreads();                    // drains chunk-c staging + chunk-c h loads
    const u16* cur = wbuf + (c & 1) * 8192;
    if (c < 11){
      u16* nxt = wbuf + ((c + 1) & 1) * 8192;
      #pragma unroll
      for (int i = 0; i < 4; ++i){
        int bl = w * 4 + i;
        int T  = (c + 1) * 2 + (bl >> 3);
        load_lds16(w1f + (size_t)(T * 8 + (bl & 7)) * 512 + lane * 8, nxt + bl * 512);
      }
    }
    short8 af[2];
    #pragma unroll
    for (int t = 0; t < 2; ++t) af[t] = pack_bf16(xa[t], xb[t]);
    if (c < 11){
      const float4* ap2 = ap + (c + 1) * 16;
      #pragma unroll
      for (int t = 0; t < 2; ++t){ xa[t] = ap2[t * 8 + q * 2]; xb[t] = ap2[t * 8 + q * 2 + 1]; }
    }
    #pragma unroll
    for (int t = 0; t < 2; ++t){
      #pragma unroll
      for (int b = 0; b < 8; ++b){
        short8 bf = *(const short8*)(cur + (t * 8 + b) * 512 + lane * 8);
        acc[b] = __builtin_amdgcn_mfma_f32_16x16x32_bf16(af[t], bf, acc[b], 0, 0, 0);
      }
    }
  }

  // ---- relu+bias -> hid A-frags (wave-private region of tail) ----
  // D: value (tok_m = q*4+r, n = 16b+ln); A2-frag addr: t2=n>>5, L2=16*((n>>3)&3)+tok_m, j=n&7
  #pragma unroll
  for (int b = 0; b < 8; ++b){
    int t2 = b >> 1;
    int q2 = ((b & 1) << 1) | (ln >> 3);
    int j  = ln & 7;
    #pragma unroll
    for (int r = 0; r < 4; ++r){
      float v = fmaxf(acc[b][r] + b1v[b], 0.0f);
      int L2 = (q2 << 4) | (q * 4 + r);
      hidf[w * 2048 + t2 * 512 + L2 * 8 + j] = (u16)(__float_as_uint(v) >> 16);
    }
  }
  __syncthreads();

  // ---- GEMM2: logits = hid @ W2 + b2 (N 200->208), B-frags straight from global (L2-hot) ----
  short8 a2[4];
  #pragma unroll
  for (int t = 0; t < 4; ++t) a2[t] = *(const short8*)(hidf + w * 2048 + t * 512 + lane * 8);
  f32x4 acc2[13];
  #pragma unroll
  for (int b = 0; b < 13; ++b) acc2[b] = (f32x4)0.0f;
  #pragma unroll
  for (int b = 0; b < 13; ++b){
    #pragma unroll
    for (int t = 0; t < 4; ++t){
      short8 bf = *(const short8*)(w2f + (size_t)(t * 13 + b) * 512 + lane * 8);
      acc2[b] = __builtin_amdgcn_mfma_f32_16x16x32_bf16(a2[t], bf, acc2[b], 0, 0, 0);
    }
  }

  // dump logits bf16 into wbuf (staging fully dead): per-wave 4096 u16, row stride 212
  #pragma unroll
  for (int b = 0; b < 13; ++b){
    #pragma unroll
    for (int r = 0; r < 4; ++r){
      float v = acc2[b][r] + b2v[b];
      wbuf[w * 4096 + (q * 4 + r) * 212 + ln + 16 * b] = (u16)(__float_as_uint(v) >> 16);
    }
  }
  __syncthreads();

  // ---- softmax + expected digit: 64 tok x 20 slots = 1280 tasks ----
  #pragma unroll
  for (int i = 0; i < 5; ++i){
    int task = tid + i * 256;
    int tok = task / 20, slot = task % 20;
    const u16* lp = wbuf + (tok >> 4) * 4096 + (tok & 15) * 212 + slot * 10;
    float v[10];
    #pragma unroll
    for (int k = 0; k < 10; ++k) v[k] = bf2f(lp[k]);
    float mx = v[0];
    #pragma unroll
    for (int k = 1; k < 10; ++k) mx = fmaxf(mx, v[k]);
    float s = 0.0f, sd = 0.0f;
    #pragma unroll
    for (int k = 0; k < 10; ++k){
      float e = __expf(v[k] - mx);
      s += e; sd += e * (float)k;
    }
    float dig = sd / s;
    digits_s[tok * 20 + slot] = dig;
    int gt = tok0 + tok;
    int o = slot / 10, k10 = slot % 10;
    dout[(size_t)25165824 + (size_t)o * 327680 + (size_t)gt * 10 + k10] = dig;
  }
  __syncthreads();

  // stage Winj part1 (first 32KB; overlays logits only) — in flight during tab stage
  #pragma unroll
  for (int i = 0; i < 8; ++i){
    int idx = tid + i * 256;                       // float4 idx 0..2047
    float4 vsrc = *(const float4*)(Winj + (size_t)idx * 4);
    *(float4*)(winj_s + (size_t)idx * 4) = vsrc;
  }

  // ---- t_p = sum_k d_k * (10^k mod p): 64 tok x 2 x 9 = 1152 tasks ----
  #pragma unroll
  for (int i = 0; i < 5; ++i){
    int task = tid + i * 256;
    if (task < 1152){
      int tok = task / 18, rm = task % 18;
      int ab = rm / 9, pi = rm % 9;
      float t = 0.0f;
      #pragma unroll
      for (int k = 0; k < 10; ++k) t += digits_s[tok * 20 + ab * 10 + k] * POW10F[pi][k];
      tab_s[tok * 18 + ab * 9 + pi] = t;
    }
  }
  __syncthreads();

  // stage part2: Winj tail (256 f4) + binj (192 f4) — overlays digits (now dead)
  {
    int idx = 2048 + (tid >> 1) + ((tid & 1) ? 224 : 0);   // spread 2 tasks/thread? keep simple:
  }
  // simple: 448 float4, threads 0..223 do 2 each
  if (tid < 224){
    #pragma unroll
    for (int i = 0; i < 2; ++i){
      int idx = 2048 + tid + i * 224;                      // 2048..2495
      if (idx < 2496){
        const float* src = (idx < 2112) ? (Winj + (size_t)idx * 4)
                                        : (binj + (size_t)(idx - 2112) * 4);
        float4 vsrc = *(const float4*)src;
        *(float4*)(winj_s + (size_t)idx * 4) = vsrc;       // binj lands at winj_s+8448 = binj_s
      }
    }
  }

  // ---- residue arithmetic, 5 ops x 64 tok = 320 tasks ----
  {
    constexpr int PR[9] = {7, 11, 13, 17, 19, 23, 29, 31, 37};
    constexpr u64 CRTC[9] = {
      35336848261ull, 224870852570ull, 114165202074ull, 218257003965ull,
      78113032998ull, 53773464745ull, 68236672504ull, 223420072876ull, 220616539143ull
    };
    #pragma unroll
    for (int rep = 0; rep < 2; ++rep){
      int task = tid + rep * 256;
      if (task < 320){
        int o5 = task >> 6, tok = task & 63;
        u64 acc64 = 0;
        #pragma unroll
        for (int pi = 0; pi < 9; ++pi){
          const int p = PR[pi];
          float ta = tab_s[tok * 18 + pi], tb = tab_s[tok * 18 + 9 + pi];
          int r;
          if (o5 == 0){
            r = __float2int_rn(ta + tb) % p;
          } else if (o5 == 1){
            int s = __float2int_rn(ta - tb) % p;
            r = (s < 0) ? s + p : s;
          } else {
            int ra = __float2int_rn(ta) % p;
            int rb = __float2int_rn(tb) % p;
            if (o5 == 2) r = (ra * rb) % p;
            else if (o5 == 3) r = modpow6(ra, rb, p);
            else r = (rb == 0) ? 0 : (ra * modpow6(rb, p - 2, p)) % p;
          }
          acc64 += (u64)r * CRTC[pi];
        }
        u64 n = acc64 % M_TOTAL;
        int sign = 0;
        u64 un = n;
        if (o5 == 1 && n > M_HALF){ sign = 1; un = M_TOTAL - n; }
        u64 pk = 0;
        #pragma unroll
        for (int k = 0; k < 10; ++k){ pk |= (un % 10ull) << (4 * k); un /= 10ull; }
        pk |= ((u64)sign) << 40;
        ops_s[tok * 5 + o5] = pk;
      }
    }
  }
  __syncthreads();

  // ---- select + MSB-reorder -> msbv[tok][0..11] floats ----
  if (tid < 64){
    int tok = tid;
    u64 pk = (op >= 0) ? ops_s[tok * 5 + op] : 0ull;
    int g[10]; int hi = -1;
    #pragma unroll
    for (int k = 0; k < 10; ++k){
      g[k] = (int)((pk >> (4 * k)) & 15ull);
      if (g[k] != 0) hi = k;
    }
    int ns = (hi >= 0) ? hi + 1 : 1;
    #pragma unroll
    for (int i = 0; i < 10; ++i)
      msbv[tok * 12 + i] = (i < ns) ? (float)g[ns - 1 - i] : -1.0f;
    msbv[tok * 12 + 10] = (float)((pk >> 40) & 1ull);
    msbv[tok * 12 + 11] = 0.0f;
  }
  __syncthreads();

  // ---- epilogue: h_prime = h + G * (msb @ Winj + binj), stream 64 rows ----
  if (tid < 192){
    float4 wv[11];
    #pragma unroll
    for (int j = 0; j < 11; ++j) wv[j] = *(const float4*)(winj_s + j * 768 + tid * 4);
    float4 bj = *(const float4*)(binj_s + tid * 4);
    const size_t base = (size_t)tok0 * 768 + tid * 4;
    #pragma unroll 4
    for (int tt = 0; tt < 64; ++tt){
      float4 m0 = *(const float4*)(msbv + tt * 12);
      float4 m1 = *(const float4*)(msbv + tt * 12 + 4);
      float4 m2 = *(const float4*)(msbv + tt * 12 + 8);
      float4 hv = *(const float4*)(h + base + (size_t)tt * 768);
      float ix = bj.x, iy = bj.y, iz = bj.z, iw = bj.w;
      ix += m0.x*wv[0].x + m0.y*wv[1].x + m0.z*wv[2].x + m0.w*wv[3].x
          + m1.x*wv[4].x + m1.y*wv[5].x + m1.z*wv[6].x + m1.w*wv[7].x
          + m2.x*wv[8].x + m2.y*wv[9].x + m2.z*wv[10].x;
      iy += m0.x*wv[0].y + m0.y*wv[1].y + m0.z*wv[2].y + m0.w*wv[3].y
          + m1.x*wv[4].y + m1.y*wv[5].y + m1.z*wv[6].y + m1.w*wv[7].y
          + m2.x*wv[8].y + m2.y*wv[9].y + m2.z*wv[10].y;
      iz += m0.x*wv[0].z + m0.y*wv[1].z + m0.z*wv[2].z + m0.w*wv[3].z
          + m1.x*wv[4].z + m1.y*wv[5].z + m1.z*wv[6].z + m1.w*wv[7].z
          + m2.x*wv[8].z + m2.y*wv[9].z + m2.z*wv[10].z;
      iw += m0.x*wv[0].w + m0.y*wv[1].w + m0.z*wv[2].w + m0.w*wv[3].w
          + m1.x*wv[4].w + m1.y*wv[5].w + m1.z*wv[6].w + m1.w*wv[7].w
          + m2.x*wv[8].w + m2.y*wv[9].w + m2.z*wv[10].w;
      float4 o;
      o.x = hv.x + G * ix; o.y = hv.y + G * iy;
      o.z = hv.z + G * iz; o.w = hv.w + G * iw;
      *(float4*)(dout + base + (size_t)tt * 768) = o;
    }
  }
}

// ---------------- launch ----------------
extern "C" void kernel_launch(void* const* d_in, const int* in_sizes, int n_in,
                              void* d_out, int out_size, void* d_ws, size_t ws_size,
                              hipStream_t stream){
  const float* h    = (const float*)d_in[0];
  const float* W1   = (const float*)d_in[1];
  const float* b1   = (const float*)d_in[2];
  const float* W2   = (const float*)d_in[3];
  const float* b2   = (const float*)d_in[4];
  const float* Winj = (const float*)d_in[5];
  const float* binj = (const float*)d_in[6];
  const float* gate = (const float*)d_in[7];
  const int*   ids  = (const int*)d_in[8];
  float* dout = (float*)d_out;

  char* ws = (char*)d_ws;
  int*   op_idx = (int*)(ws + 0);                 // 16 ints
  float* has_eq = (float*)(ws + 64);              // 16 floats
  u16*   w1f    = (u16*)(ws + 256);               // 196608 B
  u16*   w2f    = (u16*)(ws + 256 + 196608);      // 53248 B

  prelude_kernel<<<77, 256, 0, stream>>>(ids, W1, W2, op_idx, has_eq, w1f, w2f);
  mega_kernel<<<512, 256, 0, stream>>>(h, w1f, w2f, b1, b2, Winj, binj, gate,
                                       op_idx, has_eq, dout);
}